// Round 3
// baseline (2239.048 us; speedup 1.0000x reference)
//
#include <hip/hip_runtime.h>
#include <hip/hip_bf16.h>

// SelfAttention B=4,S=2048,D=512,H=8 — bf16-MFMA pipeline, fp32 softmax.
// ws-size-ADAPTIVE: processes HC heads per chunk (HC in {8,4,2,1}), largest
// that fits ws_size. Footprint = 24 MiB fixed + 32*HC MiB chunk buffers.
// out-proj accumulates per chunk: out = sum_h O_h @ Wp_h^T.

using bf16x8 = __attribute__((ext_vector_type(8))) short;
using f32x4  = __attribute__((ext_vector_type(4))) float;
typedef unsigned short u16;

__device__ __forceinline__ u16 f2bf(float f) {
  union { float f; unsigned u; } c; c.f = f;
  unsigned r = c.u + 0x7fffu + ((c.u >> 16) & 1u);  // RNE
  return (u16)(r >> 16);
}

__global__ void k_cvt(const float* __restrict__ s, u16* __restrict__ d, int n4) {
  int i = blockIdx.x * 256 + threadIdx.x;
  if (i >= n4) return;
  float4 v = reinterpret_cast<const float4*>(s)[i];
  ushort4 o;
  o.x = f2bf(v.x); o.y = f2bf(v.y); o.z = f2bf(v.z); o.w = f2bf(v.w);
  reinterpret_cast<ushort4*>(d)[i] = o;
}

// ---------------- QKV projection GEMM (NT): out = xb @ W[t*8+h]^T ------------
// grid (64, 4, 3*HC). 128x128 tile, BK=32, 4 waves.
// Outputs packed per-chunk: slot bhc = b*HC + hr.
__global__ __launch_bounds__(256) void k_gemm_qkv(
    const u16* __restrict__ xb, const u16* __restrict__ w,
    u16* __restrict__ Qc, u16* __restrict__ Kc, u16* __restrict__ VTc,
    int h0, int HC)
{
  __shared__ u16 As[128][40];
  __shared__ u16 Bs[128][40];

  const int m0 = blockIdx.x * 128;
  const int n0 = blockIdx.y * 128;
  const int zz = blockIdx.z;
  const int t  = zz / HC, hr = zz % HC;
  const int h  = h0 + hr;

  const int tid  = threadIdx.x;
  const int lane = tid & 63, wv = tid >> 6;
  const int wr = (wv >> 1) * 64, wc = (wv & 1) * 64;
  const int r16 = lane & 15, kg = lane >> 4;

  const u16* wbase = w + (size_t)(t * 8 + h) * 512 * 512;
  const int srow = tid >> 2;
  const int skq  = (tid & 3) * 8;

  const u16* ga = xb    + (size_t)(m0 + srow) * 512 + skq;
  const u16* gb = wbase + (size_t)(n0 + srow) * 512 + skq;

  f32x4 acc[4][4];
  f32x4 zero = {0.f, 0.f, 0.f, 0.f};
#pragma unroll
  for (int i = 0; i < 4; ++i)
#pragma unroll
    for (int j = 0; j < 4; ++j) acc[i][j] = zero;

  int4 ra0 = *(const int4*)(ga);
  int4 ra1 = *(const int4*)(ga + 64 * 512);
  int4 rb0 = *(const int4*)(gb);
  int4 rb1 = *(const int4*)(gb + 64 * 512);

  for (int kt = 0; kt < 16; ++kt) {
    __syncthreads();
    *(int4*)&As[srow][skq]      = ra0;
    *(int4*)&As[srow + 64][skq] = ra1;
    *(int4*)&Bs[srow][skq]      = rb0;
    *(int4*)&Bs[srow + 64][skq] = rb1;
    __syncthreads();
    if (kt < 15) {
      int ko = (kt + 1) * 32;
      ra0 = *(const int4*)(ga + ko);
      ra1 = *(const int4*)(ga + 64 * 512 + ko);
      rb0 = *(const int4*)(gb + ko);
      rb1 = *(const int4*)(gb + 64 * 512 + ko);
    }
    bf16x8 af[4], bfv[4];
#pragma unroll
    for (int i = 0; i < 4; ++i) af[i]  = *(const bf16x8*)&As[wr + i * 16 + r16][kg * 8];
#pragma unroll
    for (int j = 0; j < 4; ++j) bfv[j] = *(const bf16x8*)&Bs[wc + j * 16 + r16][kg * 8];
#pragma unroll
    for (int i = 0; i < 4; ++i)
#pragma unroll
      for (int j = 0; j < 4; ++j)
        acc[i][j] = __builtin_amdgcn_mfma_f32_16x16x32_bf16(af[i], bfv[j], acc[i][j], 0, 0, 0);
  }

  // C lane map: row=(lane>>4)*4+reg, col=lane&15  [m89/m91 verified]
#pragma unroll
  for (int i = 0; i < 4; ++i) {
    const int mbase = m0 + wr + i * 16 + kg * 4;   // 4-aligned
    const int b   = mbase >> 11;
    const int sl  = mbase & 2047;
    const int bhc = b * HC + hr;
#pragma unroll
    for (int j = 0; j < 4; ++j) {
      const int col = n0 + wc + j * 16 + r16;
      if (t == 2) {  // V transposed: VT[bhc][e=col][s]
        ushort4 o;
        o.x = f2bf(acc[i][j][0]); o.y = f2bf(acc[i][j][1]);
        o.z = f2bf(acc[i][j][2]); o.w = f2bf(acc[i][j][3]);
        *(ushort4*)&VTc[((size_t)bhc * 512 + col) * 2048 + sl] = o;
      } else {
        u16* dst = (t == 0) ? Qc : Kc;
#pragma unroll
        for (int q = 0; q < 4; ++q)
          dst[((size_t)bhc * 2048 + sl + q) * 512 + col] = f2bf(acc[i][j][q]);
      }
    }
  }
}

// ---------------- flash attention ----------------
// grid (64, 4*HC): q-tile of 32 rows, bhc.  4 waves, BC=32.
__global__ __launch_bounds__(256) void k_attn(
    const u16* __restrict__ Qc, const u16* __restrict__ Kc, const u16* __restrict__ VTc,
    const int* __restrict__ mask, u16* __restrict__ catc, int HC)
{
  __shared__ u16 Qs[32][520];
  __shared__ float S_lds[32][33];
  __shared__ u16 P_lds[32][40];
  __shared__ float m_run[32], l_run[32], alpha_s[32];

  const int qt = blockIdx.x, bhc = blockIdx.y;
  const int b = bhc / HC, hr = bhc % HC;
  const int q0 = qt * 32;

  const int tid = threadIdx.x, lane = tid & 63, wv = tid >> 6;
  const int r16 = lane & 15, kg = lane >> 4;
  const int mi = wv >> 1, ni = wv & 1;            // QK^T tile of this wave
  const int pmi = wv & 1, pc0 = (wv >> 1) * 256;  // PV rows / col-range

  const u16* Qg = Qc + ((size_t)bhc * 2048 + q0) * 512;
  for (int s = tid; s < 2048; s += 256) {
    int row = s >> 6, off = (s & 63) * 8;
    *(int4*)&Qs[row][off] = *(const int4*)(Qg + row * 512 + off);
  }
  if (tid < 32) { m_run[tid] = -__builtin_inff(); l_run[tid] = 0.f; }

  int rowm[4];
#pragma unroll
  for (int q = 0; q < 4; ++q)
    rowm[q] = mask[b * 2048 + q0 + mi * 16 + kg * 4 + q];

  f32x4 acc[16];
  f32x4 zero = {0.f, 0.f, 0.f, 0.f};
#pragma unroll
  for (int nt = 0; nt < 16; ++nt) acc[nt] = zero;

  const u16* Kg = Kc + (size_t)bhc * 2048 * 512;
  const u16* Vg = VTc + (size_t)bhc * 512 * 2048;
  const float scale = 0.044194173824159216f;  // 1/sqrt(512)

  __syncthreads();

  for (int t0 = 0; t0 < 2048; t0 += 32) {
    // ---- QK^T: this wave's 16x16 logits tile, K=512 ----
    f32x4 sa = zero;
    const u16* kbase = Kg + (size_t)(t0 + ni * 16 + r16) * 512 + kg * 8;
#pragma unroll
    for (int ks = 0; ks < 16; ++ks) {
      bf16x8 a  = *(const bf16x8*)&Qs[mi * 16 + r16][ks * 32 + kg * 8];
      bf16x8 bk = *(const bf16x8*)(kbase + ks * 32);
      sa = __builtin_amdgcn_mfma_f32_16x16x32_bf16(a, bk, sa, 0, 0, 0);
    }
    const int cm = mask[b * 2048 + t0 + ni * 16 + r16];
#pragma unroll
    for (int q = 0; q < 4; ++q) {
      float sv = (rowm[q] * cm > 0) ? sa[q] * scale : -1e9f;
      S_lds[mi * 16 + kg * 4 + q][ni * 16 + r16] = sv;
    }
    __syncthreads();   // S ready; prev-iter P_lds/alpha reads done

    // ---- online softmax: 8 threads per row ----
    {
      const int row = tid >> 3, c0 = (tid & 7) * 4;
      float s0 = S_lds[row][c0], s1 = S_lds[row][c0 + 1];
      float s2 = S_lds[row][c0 + 2], s3 = S_lds[row][c0 + 3];
      float mt = fmaxf(fmaxf(s0, s1), fmaxf(s2, s3));
      mt = fmaxf(mt, __shfl_xor(mt, 1));
      mt = fmaxf(mt, __shfl_xor(mt, 2));
      mt = fmaxf(mt, __shfl_xor(mt, 4));
      const float mo = m_run[row];
      const float mn = fmaxf(mo, mt);
      const float al = __expf(mo - mn);   // exp(-inf)=0 on first tile
      float p0 = __expf(s0 - mn), p1 = __expf(s1 - mn);
      float p2 = __expf(s2 - mn), p3 = __expf(s3 - mn);
      float ps = p0 + p1 + p2 + p3;
      ps += __shfl_xor(ps, 1); ps += __shfl_xor(ps, 2); ps += __shfl_xor(ps, 4);
      P_lds[row][c0] = f2bf(p0); P_lds[row][c0 + 1] = f2bf(p1);
      P_lds[row][c0 + 2] = f2bf(p2); P_lds[row][c0 + 3] = f2bf(p3);
      if ((tid & 7) == 0) {
        m_run[row] = mn;
        l_run[row] = l_run[row] * al + ps;
        alpha_s[row] = al;
      }
    }
    __syncthreads();   // P/alpha ready

    // ---- rescale + PV ----
    float alq[4];
#pragma unroll
    for (int q = 0; q < 4; ++q) alq[q] = alpha_s[pmi * 16 + kg * 4 + q];
#pragma unroll
    for (int nt = 0; nt < 16; ++nt) {
      acc[nt][0] *= alq[0]; acc[nt][1] *= alq[1];
      acc[nt][2] *= alq[2]; acc[nt][3] *= alq[3];
    }
    bf16x8 pa = *(const bf16x8*)&P_lds[pmi * 16 + r16][kg * 8];
    const u16* vbase = Vg + (size_t)(pc0 + r16) * 2048 + t0 + kg * 8;
#pragma unroll
    for (int nt = 0; nt < 16; ++nt) {
      bf16x8 vb = *(const bf16x8*)(vbase + (size_t)nt * 16 * 2048);
      acc[nt] = __builtin_amdgcn_mfma_f32_16x16x32_bf16(pa, vb, acc[nt], 0, 0, 0);
    }
  }

  __syncthreads();
  float rinv[4];
#pragma unroll
  for (int q = 0; q < 4; ++q) rinv[q] = 1.0f / l_run[pmi * 16 + kg * 4 + q];
  const int ldc = HC * 512;
#pragma unroll
  for (int nt = 0; nt < 16; ++nt) {
    const int col = hr * 512 + pc0 + nt * 16 + r16;
#pragma unroll
    for (int q = 0; q < 4; ++q) {
      const int row = b * 2048 + q0 + pmi * 16 + kg * 4 + q;
      catc[(size_t)row * ldc + col] = f2bf(acc[nt][q] * rinv[q]);
    }
  }
}

// ------------- output projection GEMM (NT, accumulating): out (+)= cat_c @ Wp_c^T
// grid (64, 4). K = HC*512; B k-range maps to Wp cols [h0*512, (h0+HC)*512).
__global__ __launch_bounds__(256) void k_gemm_out(
    const u16* __restrict__ A, const u16* __restrict__ Bw, float* __restrict__ out,
    int HC, int h0, int init)
{
  __shared__ u16 As[128][40];
  __shared__ u16 Bs[128][40];

  const int m0 = blockIdx.x * 128;
  const int n0 = blockIdx.y * 128;
  const int tid = threadIdx.x, lane = tid & 63, wv = tid >> 6;
  const int wr = (wv >> 1) * 64, wc = (wv & 1) * 64;
  const int r16 = lane & 15, kg = lane >> 4;
  const int srow = tid >> 2, skq = (tid & 3) * 8;
  const size_t lda = (size_t)HC * 512;
  const int nkt = HC * 16;

  const u16* ga = A  + (size_t)(m0 + srow) * lda + skq;
  const u16* gb = Bw + (size_t)(n0 + srow) * 4096 + h0 * 512 + skq;

  f32x4 acc[4][4];
  f32x4 zero = {0.f, 0.f, 0.f, 0.f};
#pragma unroll
  for (int i = 0; i < 4; ++i)
#pragma unroll
    for (int j = 0; j < 4; ++j) acc[i][j] = zero;

  int4 ra0 = *(const int4*)(ga);
  int4 ra1 = *(const int4*)(ga + 64 * lda);
  int4 rb0 = *(const int4*)(gb);
  int4 rb1 = *(const int4*)(gb + (size_t)64 * 4096);

  for (int kt = 0; kt < nkt; ++kt) {
    __syncthreads();
    *(int4*)&As[srow][skq]      = ra0;
    *(int4*)&As[srow + 64][skq] = ra1;
    *(int4*)&Bs[srow][skq]      = rb0;
    *(int4*)&Bs[srow + 64][skq] = rb1;
    __syncthreads();
    if (kt < nkt - 1) {
      int ko = (kt + 1) * 32;
      ra0 = *(const int4*)(ga + ko);
      ra1 = *(const int4*)(ga + 64 * lda + ko);
      rb0 = *(const int4*)(gb + ko);
      rb1 = *(const int4*)(gb + (size_t)64 * 4096 + ko);
    }
    bf16x8 af[4], bfv[4];
#pragma unroll
    for (int i = 0; i < 4; ++i) af[i]  = *(const bf16x8*)&As[wr + i * 16 + r16][kg * 8];
#pragma unroll
    for (int j = 0; j < 4; ++j) bfv[j] = *(const bf16x8*)&Bs[wc + j * 16 + r16][kg * 8];
#pragma unroll
    for (int i = 0; i < 4; ++i)
#pragma unroll
      for (int j = 0; j < 4; ++j)
        acc[i][j] = __builtin_amdgcn_mfma_f32_16x16x32_bf16(af[i], bfv[j], acc[i][j], 0, 0, 0);
  }

#pragma unroll
  for (int i = 0; i < 4; ++i)
#pragma unroll
    for (int j = 0; j < 4; ++j) {
      const int col = n0 + wc + j * 16 + r16;
#pragma unroll
      for (int q = 0; q < 4; ++q) {
        const int row = m0 + wr + i * 16 + kg * 4 + q;
        if (init) out[(size_t)row * 512 + col] = acc[i][j][q];
        else      out[(size_t)row * 512 + col] += acc[i][j][q];
      }
    }
}

extern "C" void kernel_launch(void* const* d_in, const int* in_sizes, int n_in,
                              void* d_out, int out_size, void* d_ws, size_t ws_size,
                              hipStream_t stream)
{
  (void)in_sizes; (void)n_in; (void)out_size;
  const float* x  = (const float*)d_in[0];
  const int* mask = (const int*)d_in[1];
  const float* Wq = (const float*)d_in[2];
  const float* Wk = (const float*)d_in[3];
  const float* Wv = (const float*)d_in[4];
  const float* Wp = (const float*)d_in[5];

  // pick largest HC in {8,4,2,1} with footprint 24 MiB + 32*HC MiB <= ws_size
  const size_t MiB = 1024 * 1024;
  int HC = 1;
  if (ws_size >= 24 * MiB + 32 * 8 * MiB)      HC = 8;
  else if (ws_size >= 24 * MiB + 32 * 4 * MiB) HC = 4;
  else if (ws_size >= 24 * MiB + 32 * 2 * MiB) HC = 2;

  char* ws = (char*)d_ws;
  size_t off = 0;
  u16* xb   = (u16*)(ws + off); off += 8 * MiB;
  u16* wqkv = (u16*)(ws + off); off += 12 * MiB;
  u16* wpb  = (u16*)(ws + off); off += 4 * MiB;
  const size_t qsz = (size_t)4 * HC * 2048 * 512 * 2;  // Q/K/VT each
  u16* Qc  = (u16*)(ws + off); off += qsz;
  u16* Kc  = (u16*)(ws + off); off += qsz;
  u16* VTc = (u16*)(ws + off); off += qsz;
  u16* catc = (u16*)(ws + off);                        // 8192 * HC*512 bf16

  k_cvt<<<4096, 256, 0, stream>>>(x,  xb, 1048576);
  k_cvt<<<2048, 256, 0, stream>>>(Wq, wqkv,           524288);
  k_cvt<<<2048, 256, 0, stream>>>(Wk, wqkv + 2097152, 524288);
  k_cvt<<<2048, 256, 0, stream>>>(Wv, wqkv + 4194304, 524288);
  k_cvt<<<2048, 256, 0, stream>>>(Wp, wpb,            524288);

  for (int h0 = 0; h0 < 8; h0 += HC) {
    k_gemm_qkv<<<dim3(64, 4, 3 * HC), 256, 0, stream>>>(xb, wqkv, Qc, Kc, VTc, h0, HC);
    k_attn<<<dim3(64, 4 * HC), 256, 0, stream>>>(Qc, Kc, VTc, mask, catc, HC);
    k_gemm_out<<<dim3(64, 4), 256, 0, stream>>>(catc, wpb, (float*)d_out, HC, h0, h0 == 0);
  }
}

// Round 4
// 1673.000 us; speedup vs baseline: 1.3383x; 1.3383x over previous
//
#include <hip/hip_runtime.h>
#include <hip/hip_bf16.h>

// SelfAttention B=4,S=2048,D=512,H=8 — bf16-MFMA, fp32 softmax.
// R4: attn v2 (KVBLK=64, LDS-staged K w/ rolling 2-deep pipeline, V preload,
//     XCD swizzle) + GEMMs on global_load_lds (m97 structure).

using bf16x8 = __attribute__((ext_vector_type(8))) short;
using f32x4  = __attribute__((ext_vector_type(4))) float;
typedef unsigned short u16;

__device__ __forceinline__ u16 f2bf(float f) {
  union { float f; unsigned u; } c; c.f = f;
  unsigned r = c.u + 0x7fffu + ((c.u >> 16) & 1u);  // RNE
  return (u16)(r >> 16);
}

__device__ __forceinline__ void gload16(const void* g, void* l) {
  __builtin_amdgcn_global_load_lds((const __attribute__((address_space(1))) unsigned int*)g,
                                   (__attribute__((address_space(3))) unsigned int*)l, 16, 0, 0);
}

__global__ void k_cvt(const float* __restrict__ s, u16* __restrict__ d, int n4) {
  int i = blockIdx.x * 256 + threadIdx.x;
  if (i >= n4) return;
  float4 v = reinterpret_cast<const float4*>(s)[i];
  ushort4 o;
  o.x = f2bf(v.x); o.y = f2bf(v.y); o.z = f2bf(v.z); o.w = f2bf(v.w);
  reinterpret_cast<ushort4*>(d)[i] = o;
}

// ---------------- QKV projection GEMM (NT): out = xb @ W[t*8+h]^T ------------
// grid (64, 4, 3*HC). 128x128 tile, BK=32, 4 waves, global_load_lds staging.
__global__ __launch_bounds__(256) void k_gemm_qkv(
    const u16* __restrict__ xb, const u16* __restrict__ w,
    u16* __restrict__ Qc, u16* __restrict__ Kc, u16* __restrict__ VTc,
    int h0, int HC)
{
  __shared__ u16 As[128][32];   // linear (global_load_lds dest)
  __shared__ u16 Bs[128][32];

  const int m0 = blockIdx.x * 128;
  const int n0 = blockIdx.y * 128;
  const int zz = blockIdx.z;
  const int t  = zz / HC, hr = zz % HC;
  const int h  = h0 + hr;

  const int tid  = threadIdx.x;
  const int lane = tid & 63, wv = tid >> 6;
  const int wr = (wv >> 1) * 64, wc = (wv & 1) * 64;
  const int r16 = lane & 15, kg = lane >> 4;

  const u16* wbase = w + (size_t)(t * 8 + h) * 512 * 512;
  const int strow = tid >> 2;          // 0..63
  const int sc4   = (tid & 3) * 8;     // u16 offset of this thread's granule

  const u16* gaa = xb    + (size_t)(m0 + strow) * 512 + sc4;
  const u16* gbb = wbase + (size_t)(n0 + strow) * 512 + sc4;
  char* AsB = (char*)&As[0][0] + wv * 1024;
  char* BsB = (char*)&Bs[0][0] + wv * 1024;

  f32x4 acc[4][4];
  f32x4 zero = {0.f, 0.f, 0.f, 0.f};
#pragma unroll
  for (int i = 0; i < 4; ++i)
#pragma unroll
    for (int j = 0; j < 4; ++j) acc[i][j] = zero;

  for (int kt = 0; kt < 16; ++kt) {
    __syncthreads();                       // prev-iter LDS reads done
    const int ko = kt * 32;
    gload16(gaa + ko,            AsB);
    gload16(gaa + 64 * 512 + ko, AsB + 4096);
    gload16(gbb + ko,            BsB);
    gload16(gbb + 64 * 512 + ko, BsB + 4096);
    __syncthreads();                       // compiler drains vmcnt before barrier
    bf16x8 af[4], bfv[4];
#pragma unroll
    for (int i = 0; i < 4; ++i) af[i]  = *(const bf16x8*)&As[wr + i * 16 + r16][kg * 8];
#pragma unroll
    for (int j = 0; j < 4; ++j) bfv[j] = *(const bf16x8*)&Bs[wc + j * 16 + r16][kg * 8];
#pragma unroll
    for (int i = 0; i < 4; ++i)
#pragma unroll
      for (int j = 0; j < 4; ++j)
        acc[i][j] = __builtin_amdgcn_mfma_f32_16x16x32_bf16(af[i], bfv[j], acc[i][j], 0, 0, 0);
  }

  // C lane map: row=(lane>>4)*4+reg, col=lane&15
#pragma unroll
  for (int i = 0; i < 4; ++i) {
    const int mbase = m0 + wr + i * 16 + kg * 4;
    const int b   = mbase >> 11;
    const int sl  = mbase & 2047;
    const int bhc = b * HC + hr;
#pragma unroll
    for (int j = 0; j < 4; ++j) {
      const int col = n0 + wc + j * 16 + r16;
      if (t == 2) {  // V transposed: VT[bhc][e=col][s]
        ushort4 o;
        o.x = f2bf(acc[i][j][0]); o.y = f2bf(acc[i][j][1]);
        o.z = f2bf(acc[i][j][2]); o.w = f2bf(acc[i][j][3]);
        *(ushort4*)&VTc[((size_t)bhc * 512 + col) * 2048 + sl] = o;
      } else {
        u16* dst = (t == 0) ? Qc : Kc;
#pragma unroll
        for (int q = 0; q < 4; ++q)
          dst[((size_t)bhc * 2048 + sl + q) * 512 + col] = f2bf(acc[i][j][q]);
      }
    }
  }
}

// ---------------- flash attention v2 ----------------
// grid (64, 4*HC) remapped XCD-bijectively. 4 waves, QBLK=32, KVBLK=64.
// K: reg-staged rolling pipeline into Ks[64][136] (d-chunks of 128, 2 ahead).
// V: fragments preloaded from global (VT layout) before softmax.
__global__ __launch_bounds__(256) void k_attn(
    const u16* __restrict__ Qc, const u16* __restrict__ Kc, const u16* __restrict__ VTc,
    const int* __restrict__ mask, u16* __restrict__ catc, int HC)
{
  __shared__ u16  Qs[32][520];
  __shared__ u16  Ks[64][136];
  __shared__ float S_lds[32][68];
  __shared__ u16  P_lds[32][72];
  __shared__ float m_run[32], l_run[32], alpha_s[32];

  // bijective XCD swizzle (nwg = 256*HC, divisible by 8)
  const int lin = blockIdx.x + (blockIdx.y << 6);
  const int per = (gridDim.y << 6) >> 3;
  const int nl  = (lin & 7) * per + (lin >> 3);
  const int qt  = nl & 63, bhc = nl >> 6;

  const int b = bhc / HC, hr = bhc % HC;
  const int q0 = qt * 32;

  const int tid = threadIdx.x, lane = tid & 63, wv = tid >> 6;
  const int r16 = lane & 15, kg = lane >> 4;

  const u16* Qg = Qc + ((size_t)bhc * 2048 + q0) * 512;
  const u16* Kg = Kc + (size_t)bhc * 2048 * 512;
  const u16* Vg = VTc + (size_t)bhc * 512 * 2048;
  const int* mrow = mask + b * 2048;

  // stage Q (32x512) once
  for (int s = tid; s < 2048; s += 256) {
    int row = s >> 6, off = (s & 63) * 8;
    *(int4*)&Qs[row][off] = *(const int4*)(Qg + row * 512 + off);
  }
  if (tid < 32) { m_run[tid] = -__builtin_inff(); l_run[tid] = 0.f; }

  // K chunk staging: chunk ci -> t0=(ci>>2)*64, d0=(ci&3)*128; 16KB via 4 int4/thread
  int4 kreg[4];
  const int kr_row = tid >> 4;            // row within 16-row group per round
  const int kr_c16 = (tid & 15) * 8;      // u16 offset of granule
  auto kload = [&](int ci) {
    const int t0 = (ci >> 2) * 64, d0 = (ci & 3) * 128;
#pragma unroll
    for (int ri = 0; ri < 4; ++ri)
      kreg[ri] = *(const int4*)(Kg + (size_t)(t0 + ri * 16 + kr_row) * 512 + d0 + kr_c16);
  };
  auto kwrite = [&]() {
#pragma unroll
    for (int ri = 0; ri < 4; ++ri)
      *(int4*)&Ks[ri * 16 + kr_row][kr_c16] = kreg[ri];
  };

  const int sm_row = tid >> 3, sm_c0 = (tid & 7) * 8;
  const int rm = mrow[q0 + sm_row];

  f32x4 acc[2][8];
  f32x4 zero = {0.f, 0.f, 0.f, 0.f};
#pragma unroll
  for (int mi = 0; mi < 2; ++mi)
#pragma unroll
    for (int nf = 0; nf < 8; ++nf) acc[mi][nf] = zero;

  const float scale = 0.044194173824159216f;  // 1/sqrt(512)

  kload(0);
  __syncthreads();            // Q staged; nothing has read Ks
  kwrite();                   // chunk 0 (implicit vmcnt wait)
  kload(1);
  __syncthreads();            // chunk 0 visible

  for (int it = 0; it < 32; ++it) {
    const int t0 = it * 64;
    f32x4 sacc[2] = {zero, zero};

    // ---- QK^T over 4 d-chunks; rolling K pipeline ----
#pragma unroll
    for (int c = 0; c < 4; ++c) {
      const int ci = it * 4 + c;
#pragma unroll
      for (int ks = 0; ks < 4; ++ks) {
        bf16x8 kb = *(const bf16x8*)&Ks[wv * 16 + r16][ks * 32 + kg * 8];
#pragma unroll
        for (int mi = 0; mi < 2; ++mi) {
          bf16x8 qa = *(const bf16x8*)&Qs[mi * 16 + r16][c * 128 + ks * 32 + kg * 8];
          sacc[mi] = __builtin_amdgcn_mfma_f32_16x16x32_bf16(qa, kb, sacc[mi], 0, 0, 0);
        }
      }
      if (c == 3) {   // publish raw S (this wave's 16-col strip)
#pragma unroll
        for (int mi = 0; mi < 2; ++mi)
#pragma unroll
          for (int q = 0; q < 4; ++q)
            S_lds[mi * 16 + kg * 4 + q][wv * 16 + r16] = sacc[mi][q];
      }
      __syncthreads();                       // all waves done reading Ks
      if (ci + 1 < 128) {
        kwrite();                            // chunk ci+1
        if (ci + 2 < 128) kload(ci + 2);
      }
      __syncthreads();                       // chunk ci+1 visible
    }

    // ---- preload V fragments (independent of softmax) ----
    bf16x8 vfrag[2][8];
#pragma unroll
    for (int ks = 0; ks < 2; ++ks)
#pragma unroll
      for (int nf = 0; nf < 8; ++nf)
        vfrag[ks][nf] = *(const bf16x8*)(Vg +
            (size_t)(wv * 128 + nf * 16 + r16) * 2048 + t0 + ks * 32 + kg * 8);

    // ---- online softmax (32 rows x 64 cols, 8 threads/row) ----
    {
      float4 sA = *(float4*)&S_lds[sm_row][sm_c0];
      float4 sB = *(float4*)&S_lds[sm_row][sm_c0 + 4];
      const int4 cA = *(const int4*)(mrow + t0 + sm_c0);
      const int4 cB = *(const int4*)(mrow + t0 + sm_c0 + 4);
      float s0 = (rm && cA.x) ? sA.x * scale : -1e9f;
      float s1 = (rm && cA.y) ? sA.y * scale : -1e9f;
      float s2 = (rm && cA.z) ? sA.z * scale : -1e9f;
      float s3 = (rm && cA.w) ? sA.w * scale : -1e9f;
      float s4 = (rm && cB.x) ? sB.x * scale : -1e9f;
      float s5 = (rm && cB.y) ? sB.y * scale : -1e9f;
      float s6 = (rm && cB.z) ? sB.z * scale : -1e9f;
      float s7 = (rm && cB.w) ? sB.w * scale : -1e9f;
      float mt = fmaxf(fmaxf(fmaxf(s0, s1), fmaxf(s2, s3)),
                       fmaxf(fmaxf(s4, s5), fmaxf(s6, s7)));
      mt = fmaxf(mt, __shfl_xor(mt, 1));
      mt = fmaxf(mt, __shfl_xor(mt, 2));
      mt = fmaxf(mt, __shfl_xor(mt, 4));
      const float mo = m_run[sm_row];
      const float mn = fmaxf(mo, mt);
      const float al = __expf(mo - mn);
      float p0 = __expf(s0 - mn), p1 = __expf(s1 - mn);
      float p2 = __expf(s2 - mn), p3 = __expf(s3 - mn);
      float p4 = __expf(s4 - mn), p5 = __expf(s5 - mn);
      float p6 = __expf(s6 - mn), p7 = __expf(s7 - mn);
      float ps = ((p0 + p1) + (p2 + p3)) + ((p4 + p5) + (p6 + p7));
      ps += __shfl_xor(ps, 1); ps += __shfl_xor(ps, 2); ps += __shfl_xor(ps, 4);
      ushort4 w0, w1;
      w0.x = f2bf(p0); w0.y = f2bf(p1); w0.z = f2bf(p2); w0.w = f2bf(p3);
      w1.x = f2bf(p4); w1.y = f2bf(p5); w1.z = f2bf(p6); w1.w = f2bf(p7);
      *(ushort4*)&P_lds[sm_row][sm_c0]     = w0;
      *(ushort4*)&P_lds[sm_row][sm_c0 + 4] = w1;
      if ((tid & 7) == 0) {
        m_run[sm_row] = mn;
        l_run[sm_row] = l_run[sm_row] * al + ps;
        alpha_s[sm_row] = al;
      }
    }
    __syncthreads();   // P/alpha ready

    // ---- rescale + PV ----
    float alq[2][4];
#pragma unroll
    for (int mi = 0; mi < 2; ++mi)
#pragma unroll
      for (int q = 0; q < 4; ++q) alq[mi][q] = alpha_s[mi * 16 + kg * 4 + q];
#pragma unroll
    for (int mi = 0; mi < 2; ++mi)
#pragma unroll
      for (int nf = 0; nf < 8; ++nf) {
        acc[mi][nf][0] *= alq[mi][0]; acc[mi][nf][1] *= alq[mi][1];
        acc[mi][nf][2] *= alq[mi][2]; acc[mi][nf][3] *= alq[mi][3];
      }
#pragma unroll
    for (int ks = 0; ks < 2; ++ks) {
      bf16x8 pa0 = *(const bf16x8*)&P_lds[r16][ks * 32 + kg * 8];
      bf16x8 pa1 = *(const bf16x8*)&P_lds[16 + r16][ks * 32 + kg * 8];
#pragma unroll
      for (int nf = 0; nf < 8; ++nf) {
        acc[0][nf] = __builtin_amdgcn_mfma_f32_16x16x32_bf16(pa0, vfrag[ks][nf], acc[0][nf], 0, 0, 0);
        acc[1][nf] = __builtin_amdgcn_mfma_f32_16x16x32_bf16(pa1, vfrag[ks][nf], acc[1][nf], 0, 0, 0);
      }
    }
  }

  // ---- epilogue ----
  float rinv[2][4];
#pragma unroll
  for (int mi = 0; mi < 2; ++mi)
#pragma unroll
    for (int q = 0; q < 4; ++q) rinv[mi][q] = 1.0f / l_run[mi * 16 + kg * 4 + q];
  const int ldc = HC * 512;
#pragma unroll
  for (int mi = 0; mi < 2; ++mi)
#pragma unroll
    for (int nf = 0; nf < 8; ++nf) {
      const int col = hr * 512 + wv * 128 + nf * 16 + r16;
#pragma unroll
      for (int q = 0; q < 4; ++q) {
        const int row = b * 2048 + q0 + mi * 16 + kg * 4 + q;
        catc[(size_t)row * ldc + col] = f2bf(acc[mi][nf][q] * rinv[mi][q]);
      }
    }
}

// ------------- output projection GEMM (NT, accumulating): out (+)= cat_c @ Wp_c^T
// grid (64, 4). K = HC*512. global_load_lds staging.
__global__ __launch_bounds__(256) void k_gemm_out(
    const u16* __restrict__ A, const u16* __restrict__ Bw, float* __restrict__ out,
    int HC, int h0, int init)
{
  __shared__ u16 As[128][32];
  __shared__ u16 Bs[128][32];

  const int m0 = blockIdx.x * 128;
  const int n0 = blockIdx.y * 128;
  const int tid = threadIdx.x, lane = tid & 63, wv = tid >> 6;
  const int wr = (wv >> 1) * 64, wc = (wv & 1) * 64;
  const int r16 = lane & 15, kg = lane >> 4;
  const int strow = tid >> 2, sc4 = (tid & 3) * 8;
  const size_t lda = (size_t)HC * 512;
  const int nkt = HC * 16;

  const u16* gaa = A  + (size_t)(m0 + strow) * lda + sc4;
  const u16* gbb = Bw + (size_t)(n0 + strow) * 4096 + h0 * 512 + sc4;
  char* AsB = (char*)&As[0][0] + wv * 1024;
  char* BsB = (char*)&Bs[0][0] + wv * 1024;

  f32x4 acc[4][4];
  f32x4 zero = {0.f, 0.f, 0.f, 0.f};
#pragma unroll
  for (int i = 0; i < 4; ++i)
#pragma unroll
    for (int j = 0; j < 4; ++j) acc[i][j] = zero;

  for (int kt = 0; kt < nkt; ++kt) {
    __syncthreads();
    const int ko = kt * 32;
    gload16(gaa + ko,            AsB);
    gload16(gaa + 64 * lda + ko, AsB + 4096);
    gload16(gbb + ko,            BsB);
    gload16(gbb + (size_t)64 * 4096 + ko, BsB + 4096);
    __syncthreads();
    bf16x8 af[4], bfv[4];
#pragma unroll
    for (int i = 0; i < 4; ++i) af[i]  = *(const bf16x8*)&As[wr + i * 16 + r16][kg * 8];
#pragma unroll
    for (int j = 0; j < 4; ++j) bfv[j] = *(const bf16x8*)&Bs[wc + j * 16 + r16][kg * 8];
#pragma unroll
    for (int i = 0; i < 4; ++i)
#pragma unroll
      for (int j = 0; j < 4; ++j)
        acc[i][j] = __builtin_amdgcn_mfma_f32_16x16x32_bf16(af[i], bfv[j], acc[i][j], 0, 0, 0);
  }

#pragma unroll
  for (int i = 0; i < 4; ++i)
#pragma unroll
    for (int j = 0; j < 4; ++j) {
      const int col = n0 + wc + j * 16 + r16;
#pragma unroll
      for (int q = 0; q < 4; ++q) {
        const int row = m0 + wr + i * 16 + kg * 4 + q;
        if (init) out[(size_t)row * 512 + col] = acc[i][j][q];
        else      out[(size_t)row * 512 + col] += acc[i][j][q];
      }
    }
}

extern "C" void kernel_launch(void* const* d_in, const int* in_sizes, int n_in,
                              void* d_out, int out_size, void* d_ws, size_t ws_size,
                              hipStream_t stream)
{
  (void)in_sizes; (void)n_in; (void)out_size;
  const float* x  = (const float*)d_in[0];
  const int* mask = (const int*)d_in[1];
  const float* Wq = (const float*)d_in[2];
  const float* Wk = (const float*)d_in[3];
  const float* Wv = (const float*)d_in[4];
  const float* Wp = (const float*)d_in[5];

  const size_t MiB = 1024 * 1024;
  int HC = 1;
  if (ws_size >= 24 * MiB + 32 * 8 * MiB)      HC = 8;
  else if (ws_size >= 24 * MiB + 32 * 4 * MiB) HC = 4;
  else if (ws_size >= 24 * MiB + 32 * 2 * MiB) HC = 2;

  char* ws = (char*)d_ws;
  size_t off = 0;
  u16* xb   = (u16*)(ws + off); off += 8 * MiB;
  u16* wqkv = (u16*)(ws + off); off += 12 * MiB;
  u16* wpb  = (u16*)(ws + off); off += 4 * MiB;
  const size_t qsz = (size_t)4 * HC * 2048 * 512 * 2;
  u16* Qc  = (u16*)(ws + off); off += qsz;
  u16* Kc  = (u16*)(ws + off); off += qsz;
  u16* VTc = (u16*)(ws + off); off += qsz;
  u16* catc = (u16*)(ws + off);

  k_cvt<<<4096, 256, 0, stream>>>(x,  xb, 1048576);
  k_cvt<<<2048, 256, 0, stream>>>(Wq, wqkv,           524288);
  k_cvt<<<2048, 256, 0, stream>>>(Wk, wqkv + 2097152, 524288);
  k_cvt<<<2048, 256, 0, stream>>>(Wv, wqkv + 4194304, 524288);
  k_cvt<<<2048, 256, 0, stream>>>(Wp, wpb,            524288);

  for (int h0 = 0; h0 < 8; h0 += HC) {
    k_gemm_qkv<<<dim3(64, 4, 3 * HC), 256, 0, stream>>>(xb, wqkv, Qc, Kc, VTc, h0, HC);
    k_attn<<<dim3(64, 4 * HC), 256, 0, stream>>>(Qc, Kc, VTc, mask, catc, HC);
    k_gemm_out<<<dim3(64, 4), 256, 0, stream>>>(catc, wpb, (float*)d_out, HC, h0, h0 == 0);
  }
}

// Round 6
// 1377.636 us; speedup vs baseline: 1.6253x; 1.2144x over previous
//
#include <hip/hip_runtime.h>
#include <hip/hip_bf16.h>

// SelfAttention B=4,S=2048,D=512,H=8 — bf16-MFMA, fp32 softmax.
// R5: attn v3 — K pre-swizzled in global (producer-side), global_load_lds
// double-buffered chunks w/ counted vmcnt(4), wave-private K rows (0 staging
// barriers), raw s_barrier (2/it), XOR-swizzled Qs, setprio on MFMA clusters.

using bf16x8 = __attribute__((ext_vector_type(8))) short;
using f32x4  = __attribute__((ext_vector_type(4))) float;
typedef unsigned short u16;

__device__ __forceinline__ u16 f2bf(float f) {
  union { float f; unsigned u; } c; c.f = f;
  unsigned r = c.u + 0x7fffu + ((c.u >> 16) & 1u);  // RNE
  return (u16)(r >> 16);
}

__device__ __forceinline__ void gload16(const void* g, void* l) {
  __builtin_amdgcn_global_load_lds((const __attribute__((address_space(1))) unsigned int*)g,
                                   (__attribute__((address_space(3))) unsigned int*)l, 16, 0, 0);
}

__global__ void k_cvt(const float* __restrict__ s, u16* __restrict__ d, int n4) {
  int i = blockIdx.x * 256 + threadIdx.x;
  if (i >= n4) return;
  float4 v = reinterpret_cast<const float4*>(s)[i];
  ushort4 o;
  o.x = f2bf(v.x); o.y = f2bf(v.y); o.z = f2bf(v.z); o.w = f2bf(v.w);
  reinterpret_cast<ushort4*>(d)[i] = o;
}

// ---------------- QKV projection GEMM (NT): out = xb @ W[t*8+h]^T ------------
// grid (64, 4, 3*HC). 128x128 tile, BK=32, 4 waves, global_load_lds staging.
// K output (t==1) is written as the SWIZZLED LDS image consumed by k_attn:
//   per bh: chunk gi = (s>>6)*4 + (d>>7); within: row=s&63, col=d&127;
//   u16 idx = gi*8192 + row*128 + (col ^ ((row&7)<<3)).
__global__ __launch_bounds__(256) void k_gemm_qkv(
    const u16* __restrict__ xb, const u16* __restrict__ w,
    u16* __restrict__ Qc, u16* __restrict__ Kc, u16* __restrict__ VTc,
    int h0, int HC)
{
  __shared__ u16 As[128][32];
  __shared__ u16 Bs[128][32];

  const int m0 = blockIdx.x * 128;
  const int n0 = blockIdx.y * 128;
  const int zz = blockIdx.z;
  const int t  = zz / HC, hr = zz % HC;
  const int h  = h0 + hr;

  const int tid  = threadIdx.x;
  const int lane = tid & 63, wv = tid >> 6;
  const int wr = (wv >> 1) * 64, wc = (wv & 1) * 64;
  const int r16 = lane & 15, kg = lane >> 4;

  const u16* wbase = w + (size_t)(t * 8 + h) * 512 * 512;
  const int strow = tid >> 2;
  const int sc4   = (tid & 3) * 8;

  const u16* gaa = xb    + (size_t)(m0 + strow) * 512 + sc4;
  const u16* gbb = wbase + (size_t)(n0 + strow) * 512 + sc4;
  char* AsB = (char*)&As[0][0] + wv * 1024;
  char* BsB = (char*)&Bs[0][0] + wv * 1024;

  f32x4 acc[4][4];
  f32x4 zero = {0.f, 0.f, 0.f, 0.f};
#pragma unroll
  for (int i = 0; i < 4; ++i)
#pragma unroll
    for (int j = 0; j < 4; ++j) acc[i][j] = zero;

  for (int kt = 0; kt < 16; ++kt) {
    __syncthreads();
    const int ko = kt * 32;
    gload16(gaa + ko,            AsB);
    gload16(gaa + 64 * 512 + ko, AsB + 4096);
    gload16(gbb + ko,            BsB);
    gload16(gbb + 64 * 512 + ko, BsB + 4096);
    __syncthreads();
    bf16x8 af[4], bfv[4];
#pragma unroll
    for (int i = 0; i < 4; ++i) af[i]  = *(const bf16x8*)&As[wr + i * 16 + r16][kg * 8];
#pragma unroll
    for (int j = 0; j < 4; ++j) bfv[j] = *(const bf16x8*)&Bs[wc + j * 16 + r16][kg * 8];
#pragma unroll
    for (int i = 0; i < 4; ++i)
#pragma unroll
      for (int j = 0; j < 4; ++j)
        acc[i][j] = __builtin_amdgcn_mfma_f32_16x16x32_bf16(af[i], bfv[j], acc[i][j], 0, 0, 0);
  }

  // C lane map: row=(lane>>4)*4+reg, col=lane&15
#pragma unroll
  for (int i = 0; i < 4; ++i) {
    const int mbase = m0 + wr + i * 16 + kg * 4;
    const int b   = mbase >> 11;
    const int sl  = mbase & 2047;
    const int bhc = b * HC + hr;
#pragma unroll
    for (int j = 0; j < 4; ++j) {
      const int col = n0 + wc + j * 16 + r16;
      if (t == 2) {        // V transposed: VT[bhc][e=col][s]
        ushort4 o;
        o.x = f2bf(acc[i][j][0]); o.y = f2bf(acc[i][j][1]);
        o.z = f2bf(acc[i][j][2]); o.w = f2bf(acc[i][j][3]);
        *(ushort4*)&VTc[((size_t)bhc * 512 + col) * 2048 + sl] = o;
      } else if (t == 1) { // K: swizzled chunk image
#pragma unroll
        for (int q = 0; q < 4; ++q) {
          const int s   = sl + q;
          const int row = s & 63;
          const size_t idx = ((size_t)bhc << 20)
                           + (size_t)((s >> 6) * 4 + (col >> 7)) * 8192
                           + row * 128 + ((col & 127) ^ ((row & 7) << 3));
          Kc[idx] = f2bf(acc[i][j][q]);
        }
      } else {             // Q: plain row-major [bhc][s][e]
#pragma unroll
        for (int q = 0; q < 4; ++q)
          Qc[((size_t)bhc * 2048 + sl + q) * 512 + col] = f2bf(acc[i][j][q]);
      }
    }
  }
}

// ---------------- flash attention v3 ----------------
// grid (64, 4*HC) XCD-swizzled. 4 waves, QBLK=32, KVBLK=64, d-chunks of 128.
// K: gload_lds from pre-swizzled global, 2 buffers, 2 chunks in flight,
//    counted vmcnt(4); wave-private rows -> no staging barriers.
// Barriers: 2 raw s_barrier per it (S publish, P publish).
__global__ __launch_bounds__(256) void k_attn(
    const u16* __restrict__ Qc, const u16* __restrict__ Kc, const u16* __restrict__ VTc,
    const int* __restrict__ mask, u16* __restrict__ catc, int HC)
{
  __shared__ u16  Qs[32 * 512];      // XOR-swizzled rows (32 KB)
  __shared__ u16  Ks[2 * 8192];      // 2 chunk buffers [64][128] swizzled (32 KB)
  __shared__ float S_lds[32][68];
  __shared__ u16  P_lds[32][72];
  __shared__ float m_run[32], l_run[32], alpha_s[32];

  // bijective XCD swizzle (nwg = 256*HC, divisible by 8)
  const int lin = blockIdx.x + (blockIdx.y << 6);
  const int per = (gridDim.y << 6) >> 3;
  const int nl  = (lin & 7) * per + (lin >> 3);
  const int qt  = nl & 63, bhc = nl >> 6;

  const int b = bhc / HC, hr = bhc % HC;
  const int q0 = qt * 32;

  const int tid = threadIdx.x, lane = tid & 63, wv = tid >> 6;
  const int r16 = lane & 15, kg = lane >> 4;

  const u16* Qg = Qc + ((size_t)bhc * 2048 + q0) * 512;
  const u16* Kg = Kc + ((size_t)bhc << 20);
  const u16* Vg = VTc + (size_t)bhc * 512 * 2048;
  const int* mrow = mask + b * 2048;

  // stage Q swizzled
  for (int s = tid; s < 2048; s += 256) {
    const int row = s >> 6, col = (s & 63) * 8;
    *(int4*)&Qs[row * 512 + (col ^ ((row & 7) << 3))] =
        *(const int4*)(Qg + row * 512 + col);
  }
  if (tid < 32) { m_run[tid] = -__builtin_inff(); l_run[tid] = 0.f; }

  // K chunk issue: wave wv loads exactly rows 16wv..16wv+15 (the rows it reads)
  auto kissue = [&](int gi, int cur) {
    const u16* g = Kg + (size_t)gi * 8192 + wv * 2048 + lane * 8;
    u16* l = &Ks[cur * 8192 + wv * 2048];
#pragma unroll
    for (int r = 0; r < 4; ++r)
      gload16(g + r * 512, l + r * 512);
  };

  kissue(0, 0);
  kissue(1, 1);

  asm volatile("s_waitcnt lgkmcnt(0)" ::: "memory");
  __builtin_amdgcn_s_barrier();    // Q visible; K gloads stay in flight

  const int sm_row = tid >> 3, sm_c0 = (tid & 7) * 8;
  const int rm = mrow[q0 + sm_row];
  const int krow = wv * 16 + r16;
  const int kswz = (krow & 7) << 3;

  f32x4 acc[2][8];
  f32x4 zero = {0.f, 0.f, 0.f, 0.f};
#pragma unroll
  for (int mi = 0; mi < 2; ++mi)
#pragma unroll
    for (int nf = 0; nf < 8; ++nf) acc[mi][nf] = zero;

  const float scale = 0.044194173824159216f;  // 1/sqrt(512)

  for (int it = 0; it < 32; ++it) {
    const int t0 = it * 64;
    f32x4 sacc[2] = {zero, zero};

    // ---- QK^T over 4 d-chunks; barrier-free 2-deep K pipeline ----
#pragma unroll
    for (int c = 0; c < 4; ++c) {
      const int gi = it * 4 + c;
      const int cur = gi & 1;
      asm volatile("s_waitcnt vmcnt(4)" ::: "memory");  // chunk gi landed
      __builtin_amdgcn_s_setprio(1);
#pragma unroll
      for (int ks = 0; ks < 4; ++ks) {
        bf16x8 kb = *(const bf16x8*)&Ks[cur * 8192 + krow * 128 + ((ks * 32 + kg * 8) ^ kswz)];
#pragma unroll
        for (int mi = 0; mi < 2; ++mi) {
          const int qrow = mi * 16 + r16;
          bf16x8 qa = *(const bf16x8*)&Qs[qrow * 512 +
              ((c * 128 + ks * 32 + kg * 8) ^ ((qrow & 7) << 3))];
          sacc[mi] = __builtin_amdgcn_mfma_f32_16x16x32_bf16(qa, kb, sacc[mi], 0, 0, 0);
        }
      }
      __builtin_amdgcn_s_setprio(0);
      if (c == 3) {  // publish raw S strip
#pragma unroll
        for (int mi = 0; mi < 2; ++mi)
#pragma unroll
          for (int q = 0; q < 4; ++q)
            S_lds[mi * 16 + kg * 4 + q][wv * 16 + r16] = sacc[mi][q];
      }
      asm volatile("s_waitcnt lgkmcnt(0)" ::: "memory");  // my ds_reads/writes done
      __builtin_amdgcn_sched_barrier(0);
      if (gi + 2 < 128) kissue(gi + 2, cur);              // overwrite-safe (wave-private)
    }
    __builtin_amdgcn_s_barrier();    // S visible (lgkm drained above); K loads in flight

    // ---- V fragment preload (L2-resident, independent of softmax) ----
    bf16x8 vfrag[2][8];
#pragma unroll
    for (int ks = 0; ks < 2; ++ks)
#pragma unroll
      for (int nf = 0; nf < 8; ++nf)
        vfrag[ks][nf] = *(const bf16x8*)(Vg +
            (size_t)(wv * 128 + nf * 16 + r16) * 2048 + t0 + ks * 32 + kg * 8);

    // ---- online softmax (32 rows x 64 cols, 8 threads/row) ----
    {
      float4 sA = *(float4*)&S_lds[sm_row][sm_c0];
      float4 sB = *(float4*)&S_lds[sm_row][sm_c0 + 4];
      const int4 cA = *(const int4*)(mrow + t0 + sm_c0);
      const int4 cB = *(const int4*)(mrow + t0 + sm_c0 + 4);
      float s0 = (rm && cA.x) ? sA.x * scale : -1e9f;
      float s1 = (rm && cA.y) ? sA.y * scale : -1e9f;
      float s2 = (rm && cA.z) ? sA.z * scale : -1e9f;
      float s3 = (rm && cA.w) ? sA.w * scale : -1e9f;
      float s4 = (rm && cB.x) ? sB.x * scale : -1e9f;
      float s5 = (rm && cB.y) ? sB.y * scale : -1e9f;
      float s6 = (rm && cB.z) ? sB.z * scale : -1e9f;
      float s7 = (rm && cB.w) ? sB.w * scale : -1e9f;
      float mt = fmaxf(fmaxf(fmaxf(s0, s1), fmaxf(s2, s3)),
                       fmaxf(fmaxf(s4, s5), fmaxf(s6, s7)));
      mt = fmaxf(mt, __shfl_xor(mt, 1));
      mt = fmaxf(mt, __shfl_xor(mt, 2));
      mt = fmaxf(mt, __shfl_xor(mt, 4));
      const float mo = m_run[sm_row];
      const float mn = fmaxf(mo, mt);
      const float al = __expf(mo - mn);
      float p0 = __expf(s0 - mn), p1 = __expf(s1 - mn);
      float p2 = __expf(s2 - mn), p3 = __expf(s3 - mn);
      float p4 = __expf(s4 - mn), p5 = __expf(s5 - mn);
      float p6 = __expf(s6 - mn), p7 = __expf(s7 - mn);
      float ps = ((p0 + p1) + (p2 + p3)) + ((p4 + p5) + (p6 + p7));
      ps += __shfl_xor(ps, 1); ps += __shfl_xor(ps, 2); ps += __shfl_xor(ps, 4);
      ushort4 w0, w1;
      w0.x = f2bf(p0); w0.y = f2bf(p1); w0.z = f2bf(p2); w0.w = f2bf(p3);
      w1.x = f2bf(p4); w1.y = f2bf(p5); w1.z = f2bf(p6); w1.w = f2bf(p7);
      *(ushort4*)&P_lds[sm_row][sm_c0]     = w0;
      *(ushort4*)&P_lds[sm_row][sm_c0 + 4] = w1;
      if ((tid & 7) == 0) {
        m_run[sm_row] = mn;
        l_run[sm_row] = l_run[sm_row] * al + ps;
        alpha_s[sm_row] = al;
      }
    }
    asm volatile("s_waitcnt lgkmcnt(0)" ::: "memory");
    __builtin_amdgcn_s_barrier();    // P/alpha visible

    // ---- rescale + PV ----
    float alq[2][4];
#pragma unroll
    for (int mi = 0; mi < 2; ++mi)
#pragma unroll
      for (int q = 0; q < 4; ++q) alq[mi][q] = alpha_s[mi * 16 + kg * 4 + q];
#pragma unroll
    for (int mi = 0; mi < 2; ++mi)
#pragma unroll
      for (int nf = 0; nf < 8; ++nf) {
        acc[mi][nf][0] *= alq[mi][0]; acc[mi][nf][1] *= alq[mi][1];
        acc[mi][nf][2] *= alq[mi][2]; acc[mi][nf][3] *= alq[mi][3];
      }
    __builtin_amdgcn_s_setprio(1);
#pragma unroll
    for (int ks = 0; ks < 2; ++ks) {
      bf16x8 pa0 = *(const bf16x8*)&P_lds[r16][ks * 32 + kg * 8];
      bf16x8 pa1 = *(const bf16x8*)&P_lds[16 + r16][ks * 32 + kg * 8];
#pragma unroll
      for (int nf = 0; nf < 8; ++nf) {
        acc[0][nf] = __builtin_amdgcn_mfma_f32_16x16x32_bf16(pa0, vfrag[ks][nf], acc[0][nf], 0, 0, 0);
        acc[1][nf] = __builtin_amdgcn_mfma_f32_16x16x32_bf16(pa1, vfrag[ks][nf], acc[1][nf], 0, 0, 0);
      }
    }
    __builtin_amdgcn_s_setprio(0);
  }

  // ---- epilogue ----
  float rinv[2][4];
#pragma unroll
  for (int mi = 0; mi < 2; ++mi)
#pragma unroll
    for (int q = 0; q < 4; ++q) rinv[mi][q] = 1.0f / l_run[mi * 16 + kg * 4 + q];
  const int ldc = HC * 512;
#pragma unroll
  for (int mi = 0; mi < 2; ++mi)
#pragma unroll
    for (int nf = 0; nf < 8; ++nf) {
      const int col = hr * 512 + wv * 128 + nf * 16 + r16;
#pragma unroll
      for (int q = 0; q < 4; ++q) {
        const int row = b * 2048 + q0 + mi * 16 + kg * 4 + q;
        catc[(size_t)row * ldc + col] = f2bf(acc[mi][nf][q] * rinv[mi][q]);
      }
    }
}

// ------------- output projection GEMM (NT, accumulating): out (+)= cat_c @ Wp_c^T
__global__ __launch_bounds__(256) void k_gemm_out(
    const u16* __restrict__ A, const u16* __restrict__ Bw, float* __restrict__ out,
    int HC, int h0, int init)
{
  __shared__ u16 As[128][32];
  __shared__ u16 Bs[128][32];

  const int m0 = blockIdx.x * 128;
  const int n0 = blockIdx.y * 128;
  const int tid = threadIdx.x, lane = tid & 63, wv = tid >> 6;
  const int wr = (wv >> 1) * 64, wc = (wv & 1) * 64;
  const int r16 = lane & 15, kg = lane >> 4;
  const int strow = tid >> 2, sc4 = (tid & 3) * 8;
  const size_t lda = (size_t)HC * 512;
  const int nkt = HC * 16;

  const u16* gaa = A  + (size_t)(m0 + strow) * lda + sc4;
  const u16* gbb = Bw + (size_t)(n0 + strow) * 4096 + h0 * 512 + sc4;
  char* AsB = (char*)&As[0][0] + wv * 1024;
  char* BsB = (char*)&Bs[0][0] + wv * 1024;

  f32x4 acc[4][4];
  f32x4 zero = {0.f, 0.f, 0.f, 0.f};
#pragma unroll
  for (int i = 0; i < 4; ++i)
#pragma unroll
    for (int j = 0; j < 4; ++j) acc[i][j] = zero;

  for (int kt = 0; kt < nkt; ++kt) {
    __syncthreads();
    const int ko = kt * 32;
    gload16(gaa + ko,            AsB);
    gload16(gaa + 64 * lda + ko, AsB + 4096);
    gload16(gbb + ko,            BsB);
    gload16(gbb + (size_t)64 * 4096 + ko, BsB + 4096);
    __syncthreads();
    bf16x8 af[4], bfv[4];
#pragma unroll
    for (int i = 0; i < 4; ++i) af[i]  = *(const bf16x8*)&As[wr + i * 16 + r16][kg * 8];
#pragma unroll
    for (int j = 0; j < 4; ++j) bfv[j] = *(const bf16x8*)&Bs[wc + j * 16 + r16][kg * 8];
#pragma unroll
    for (int i = 0; i < 4; ++i)
#pragma unroll
      for (int j = 0; j < 4; ++j)
        acc[i][j] = __builtin_amdgcn_mfma_f32_16x16x32_bf16(af[i], bfv[j], acc[i][j], 0, 0, 0);
  }

#pragma unroll
  for (int i = 0; i < 4; ++i)
#pragma unroll
    for (int j = 0; j < 4; ++j) {
      const int col = n0 + wc + j * 16 + r16;
#pragma unroll
      for (int q = 0; q < 4; ++q) {
        const int row = m0 + wr + i * 16 + kg * 4 + q;
        if (init) out[(size_t)row * 512 + col] = acc[i][j][q];
        else      out[(size_t)row * 512 + col] += acc[i][j][q];
      }
    }
}

extern "C" void kernel_launch(void* const* d_in, const int* in_sizes, int n_in,
                              void* d_out, int out_size, void* d_ws, size_t ws_size,
                              hipStream_t stream)
{
  (void)in_sizes; (void)n_in; (void)out_size;
  const float* x  = (const float*)d_in[0];
  const int* mask = (const int*)d_in[1];
  const float* Wq = (const float*)d_in[2];
  const float* Wk = (const float*)d_in[3];
  const float* Wv = (const float*)d_in[4];
  const float* Wp = (const float*)d_in[5];

  const size_t MiB = 1024 * 1024;
  int HC = 1;
  if (ws_size >= 24 * MiB + 32 * 8 * MiB)      HC = 8;
  else if (ws_size >= 24 * MiB + 32 * 4 * MiB) HC = 4;
  else if (ws_size >= 24 * MiB + 32 * 2 * MiB) HC = 2;

  char* ws = (char*)d_ws;
  size_t off = 0;
  u16* xb   = (u16*)(ws + off); off += 8 * MiB;
  u16* wqkv = (u16*)(ws + off); off += 12 * MiB;
  u16* wpb  = (u16*)(ws + off); off += 4 * MiB;
  const size_t qsz = (size_t)4 * HC * 2048 * 512 * 2;
  u16* Qc  = (u16*)(ws + off); off += qsz;
  u16* Kc  = (u16*)(ws + off); off += qsz;
  u16* VTc = (u16*)(ws + off); off += qsz;
  u16* catc = (u16*)(ws + off);

  k_cvt<<<4096, 256, 0, stream>>>(x,  xb, 1048576);
  k_cvt<<<2048, 256, 0, stream>>>(Wq, wqkv,           524288);
  k_cvt<<<2048, 256, 0, stream>>>(Wk, wqkv + 2097152, 524288);
  k_cvt<<<2048, 256, 0, stream>>>(Wv, wqkv + 4194304, 524288);
  k_cvt<<<2048, 256, 0, stream>>>(Wp, wpb,            524288);

  for (int h0 = 0; h0 < 8; h0 += HC) {
    k_gemm_qkv<<<dim3(64, 4, 3 * HC), 256, 0, stream>>>(xb, wqkv, Qc, Kc, VTc, h0, HC);
    k_attn<<<dim3(64, 4 * HC), 256, 0, stream>>>(Qc, Kc, VTc, mask, catc, HC);
    k_gemm_out<<<dim3(64, 4), 256, 0, stream>>>(catc, wpb, (float*)d_out, HC, h0, h0 == 0);
  }
}